// Round 7
// baseline (1543.103 us; speedup 1.0000x reference)
//
#include <hip/hip_runtime.h>
#include <cstddef>
#include <cstdint>

#define Tn 512
#define Bn 512

typedef float f32x2 __attribute__((ext_vector_type(2)));

__device__ __forceinline__ float rlane(float v, int lane) {
    return __uint_as_float((unsigned)__builtin_amdgcn_readlane((int)__float_as_uint(v), lane));
}
__device__ __forceinline__ float sigm(float x) { return 1.0f / (1.0f + __expf(-x)); }
// tanh(x) = 1 - 2/(1+e^{2x}); inf-safe at both ends
__device__ __forceinline__ float tanhf_(float x) { return 1.0f - 2.0f / (1.0f + __expf(2.0f * x)); }

// LDS-visibility barrier WITHOUT the __syncthreads vmcnt(0) drain.
#define BAR_LGKM() asm volatile("s_waitcnt lgkmcnt(0)\n\ts_barrier" ::: "memory")
// Pin a value into arch-VGPR class (works at waves_per_eu=1 budget — R5).
#define PIN(v) asm volatile("" : "+v"(v))

#define ACT(GI, GF, GG, GO, C, H)                              \
    do {                                                       \
        C = sigm(GF) * (C) + sigm(GI) * tanhf_(GG);            \
        H = sigm(GO) * tanhf_(C);                              \
    } while (0)

// Full K=64 dot against in-register gate-pair weights wp01/wp23.
// 64 readlane + 128 v_pk_fma_f32; 2 accumulator pairs for ILP.
// Yields g01 = {gate_i, gate_f}, g23 = {gate_g, gate_o} partial sums.
#define DOT64(S)                                                              \
    do {                                                                      \
        f32x2 aa = {0.f, 0.f}, ab = {0.f, 0.f};                               \
        f32x2 ba = {0.f, 0.f}, bb = {0.f, 0.f};                               \
        _Pragma("unroll")                                                     \
        for (int k = 0; k < 64; k += 2) {                                     \
            const float v0 = rlane((S), k);                                   \
            const float v1 = rlane((S), k + 1);                               \
            aa = __builtin_elementwise_fma((f32x2){v0, v0}, wp01[k], aa);     \
            ba = __builtin_elementwise_fma((f32x2){v0, v0}, wp23[k], ba);     \
            ab = __builtin_elementwise_fma((f32x2){v1, v1}, wp01[k + 1], ab); \
            bb = __builtin_elementwise_fma((f32x2){v1, v1}, wp23[k + 1], bb); \
        }                                                                     \
        g01 = aa + ab;                                                        \
        g23 = ba + bb;                                                        \
    } while (0)

// ---------------------------------------------------------------------------
// Layer 0 (IN=1). ONE WAVE per (b,dir) chain, full K=64 in-register:
// wp01/wp23[64] f32x2 = 128 VGPRs, live ~190 << 512 budget of (64,1) —
// the proven-safe no-AGPR-split config (R5). ZERO barriers, zero partial
// exchange: per step = 64 readlane + 128 pk_fma + activation + 1 store.
// 1024 blocks -> 4 waves/CU (pool 2048/~190 = 10, trivially resident).
// ---------------------------------------------------------------------------
__global__ __launch_bounds__(64, 1) void k_lstm_l0(
    const float* __restrict__ x,
    const float* __restrict__ wih_f, const float* __restrict__ whh_f,
    const float* __restrict__ bih_f, const float* __restrict__ bhh_f,
    const float* __restrict__ wih_r, const float* __restrict__ whh_r,
    const float* __restrict__ bih_r, const float* __restrict__ bhh_r,
    float* __restrict__ h0out)
{
    const int j   = threadIdx.x;     // hidden unit
    const int b   = blockIdx.x >> 1;
    const int dir = blockIdx.x & 1;

    const float* __restrict__ wih = dir ? wih_r : wih_f;
    const float* __restrict__ whh = dir ? whh_r : whh_f;
    const float* __restrict__ bih = dir ? bih_r : bih_f;
    const float* __restrict__ bhh = dir ? bhh_r : bhh_f;

    __shared__ float xs[Tn];   // 2 KB; single wave -> no barrier needed
    #pragma unroll
    for (int i = 0; i < Tn / 64; ++i) xs[i * 64 + j] = x[(size_t)b * Tn + i * 64 + j];

    // gate-pair weights, fully in VGPRs
    f32x2 wp01[64], wp23[64];
    #pragma unroll
    for (int k = 0; k < 64; ++k) {
        wp01[k] = (f32x2){whh[(size_t)(  0 + j) * 64 + k], whh[(size_t)( 64 + j) * 64 + k]};
        wp23[k] = (f32x2){whh[(size_t)(128 + j) * 64 + k], whh[(size_t)(192 + j) * 64 + k]};
        PIN(wp01[k]); PIN(wp23[k]);
    }
    const f32x2 wx01   = {wih[j],              wih[64 + j]};
    const f32x2 wx23   = {wih[128 + j],        wih[192 + j]};
    const f32x2 bias01 = {bih[j] + bhh[j],     bih[64 + j] + bhh[64 + j]};
    const f32x2 bias23 = {bih[128 + j] + bhh[128 + j], bih[192 + j] + bhh[192 + j]};

    float h = 0.0f, c = 0.0f;
    float* __restrict__ outp = h0out + (size_t)b * Tn * 128 + dir * 64 + j;

    for (int s = 0; s < Tn; ++s) {
        const int t = dir ? (Tn - 1 - s) : s;
        const float xt = xs[t];            // uniform-addr LDS broadcast
        f32x2 g01, g23;
        DOT64(h);
        const f32x2 xt2 = {xt, xt};
        g01 = __builtin_elementwise_fma(xt2, wx01, g01 + bias01);
        g23 = __builtin_elementwise_fma(xt2, wx23, g23 + bias23);
        float gi = g01.x, gf = g01.y, gg = g23.x, go = g23.y;
        ACT(gi, gf, gg, go, c, h);
        outp[(size_t)t * 128] = h;         // store floats on vmcnt, never waited
    }
}

// ---------------------------------------------------------------------------
// Layer 1 forward scan, fused input GEMM (K = 128 x + 64 h = 192).
// THREE waves per batch element: wv0 -> x1[0:64), wv1 -> x1[64:128) (pure
// producers, 2-deep global prefetch, decoupled via double-buffered LDS),
// wv2 -> h[0:64) AND sole reducer (its own partial never leaves registers:
// reduce = 2 x ds_read_b128 + pk adds + activation). ONE lgkm-only barrier
// per step. Weights 128 VGPRs/wave, live ~200 << 512 budget of (192,1).
// 512 blocks x 192 thr -> 2 blocks/CU (6 waves, pool 2048/~200 = 10). 
// ---------------------------------------------------------------------------
__global__ __launch_bounds__(192, 1) void k_lstm_l1f(
    const float* __restrict__ h0in,
    const float* __restrict__ wih, const float* __restrict__ whh,
    const float* __restrict__ bih, const float* __restrict__ bhh,
    float* __restrict__ h1last)
{
    const int tid = threadIdx.x;
    const int wv  = tid >> 6;        // 0,1 = x producers; 2 = h + reducer
    const int j   = tid & 63;
    const int b   = blockIdx.x;

    __shared__ float4 part[2][2][64];   // [buf][producer][unit], 4 KB

    // weight bases (wave-uniform select; array writes unconditional)
    const float *w0b, *w1b, *w2b, *w3b;
    if (wv == 2) {
        w0b = whh + (size_t)(  0 + j) * 64;
        w1b = whh + (size_t)( 64 + j) * 64;
        w2b = whh + (size_t)(128 + j) * 64;
        w3b = whh + (size_t)(192 + j) * 64;
    } else {
        const int o = wv * 64;
        w0b = wih + (size_t)(  0 + j) * 128 + o;
        w1b = wih + (size_t)( 64 + j) * 128 + o;
        w2b = wih + (size_t)(128 + j) * 128 + o;
        w3b = wih + (size_t)(192 + j) * 128 + o;
    }
    f32x2 wp01[64], wp23[64];
    #pragma unroll
    for (int k = 0; k < 64; ++k) {
        wp01[k] = (f32x2){w0b[k], w1b[k]};
        wp23[k] = (f32x2){w2b[k], w3b[k]};
        PIN(wp01[k]); PIN(wp23[k]);
    }
    const f32x2 bias01 = {bih[j] + bhh[j],               bih[64 + j] + bhh[64 + j]};
    const f32x2 bias23 = {bih[128 + j] + bhh[128 + j],   bih[192 + j] + bhh[192 + j]};

    const float* __restrict__ xrow = h0in + (size_t)b * Tn * 128 + (wv & 1) * 64 + j;

    // producers: 2-deep rotating register prefetch (BAR never drains vmcnt)
    float s0 = 0.0f, s1 = 0.0f;
    if (wv < 2) { s0 = xrow[0]; s1 = xrow[128]; }
    float h = 0.0f, c = 0.0f;

    for (int t = 0; t < Tn; ++t) {
        const int bf = t & 1;
        float s2 = 0.0f;
        if (wv < 2) {
            const int tp = (t + 2 < Tn) ? t + 2 : Tn - 1;
            s2 = xrow[(size_t)tp * 128];
        }
        f32x2 g01, g23;
        if (wv == 0)      { DOT64(s0); part[bf][0][j] = make_float4(g01.x, g01.y, g23.x, g23.y); }
        else if (wv == 1) { DOT64(s0); part[bf][1][j] = make_float4(g01.x, g01.y, g23.x, g23.y); }
        else              { DOT64(h); }    // reducer's own partial stays in regs
        BAR_LGKM();
        if (wv == 2) {
            const float4 q0 = part[bf][0][j];
            const float4 q1 = part[bf][1][j];
            g01 = g01 + (f32x2){q0.x, q0.y} + (f32x2){q1.x, q1.y} + bias01;
            g23 = g23 + (f32x2){q0.z, q0.w} + (f32x2){q1.z, q1.w} + bias23;
            float gi = g01.x, gf = g01.y, gg = g23.x, go = g23.y;
            ACT(gi, gf, gg, go, c, h);
        }
        s0 = s1; s1 = s2;
    }
    if (wv == 2) h1last[(size_t)b * 64 + j] = h;
}

// ---------------------------------------------------------------------------
// Layer-1 backward direction collapses to ONE step at t=T-1 (zero init state),
// then the final FC. One wave per batch element.
// ---------------------------------------------------------------------------
__global__ __launch_bounds__(64, 1) void k_l1r_fc(
    const float* __restrict__ h0in,
    const float* __restrict__ wihr,
    const float* __restrict__ bihr, const float* __restrict__ bhhr,
    const float* __restrict__ h1last,
    const float* __restrict__ fcw, const float* __restrict__ fcb,
    float* __restrict__ out)
{
    const int b = blockIdx.x;
    const int j = threadIdx.x;
    const float* __restrict__ xrow = h0in + ((size_t)b * Tn + (Tn - 1)) * 128;
    const float x1a = xrow[j];
    const float x1b = xrow[64 + j];
    float acc[4];
    #pragma unroll
    for (int g = 0; g < 4; ++g) {
        const int r = g * 64 + j;
        float a = bihr[r] + bhhr[r];
        const float* __restrict__ wr = wihr + (size_t)r * 128;
        #pragma unroll
        for (int d4 = 0; d4 < 16; ++d4) {
            const float4 w4 = *reinterpret_cast<const float4*>(&wr[d4 * 4]);
            a = fmaf(rlane(x1a, d4 * 4 + 0), w4.x, a);
            a = fmaf(rlane(x1a, d4 * 4 + 1), w4.y, a);
            a = fmaf(rlane(x1a, d4 * 4 + 2), w4.z, a);
            a = fmaf(rlane(x1a, d4 * 4 + 3), w4.w, a);
        }
        #pragma unroll
        for (int d4 = 0; d4 < 16; ++d4) {
            const float4 w4 = *reinterpret_cast<const float4*>(&wr[64 + d4 * 4]);
            a = fmaf(rlane(x1b, d4 * 4 + 0), w4.x, a);
            a = fmaf(rlane(x1b, d4 * 4 + 1), w4.y, a);
            a = fmaf(rlane(x1b, d4 * 4 + 2), w4.z, a);
            a = fmaf(rlane(x1b, d4 * 4 + 3), w4.w, a);
        }
        acc[g] = a;
    }
    const float cr = sigm(acc[0]) * tanhf_(acc[2]);
    const float hr = sigm(acc[3]) * tanhf_(cr);
    float v = h1last[(size_t)b * 64 + j] * fcw[j] + hr * fcw[64 + j];
    #pragma unroll
    for (int off = 32; off > 0; off >>= 1) v += __shfl_xor(v, off, 64);
    if (j == 0) out[b] = v + fcb[0];
}

// ---------------------------------------------------------------------------
extern "C" void kernel_launch(void* const* d_in, const int* in_sizes, int n_in,
                              void* d_out, int out_size, void* d_ws, size_t ws_size,
                              hipStream_t stream)
{
    const float* x       = (const float*)d_in[0];
    const float* wih_l0  = (const float*)d_in[1];
    const float* whh_l0  = (const float*)d_in[2];
    const float* bih_l0  = (const float*)d_in[3];
    const float* bhh_l0  = (const float*)d_in[4];
    const float* wih_l0r = (const float*)d_in[5];
    const float* whh_l0r = (const float*)d_in[6];
    const float* bih_l0r = (const float*)d_in[7];
    const float* bhh_l0r = (const float*)d_in[8];
    const float* wih_l1  = (const float*)d_in[9];
    const float* whh_l1  = (const float*)d_in[10];
    const float* bih_l1  = (const float*)d_in[11];
    const float* bhh_l1  = (const float*)d_in[12];
    const float* wih_l1r = (const float*)d_in[13];
    const float* whh_l1r = (const float*)d_in[14];
    const float* bih_l1r = (const float*)d_in[15];
    const float* bhh_l1r = (const float*)d_in[16];
    const float* fcw     = (const float*)d_in[17];
    const float* fcb     = (const float*)d_in[18];
    (void)whh_l1r; (void)in_sizes; (void)n_in; (void)out_size;

    // ws layout: h0 [512][512][128] f32 (134.2 MB) + h1last [512][64] f32
    float* h0     = (float*)d_ws;
    float* h1last = h0 + (size_t)Bn * Tn * 128;
    (void)ws_size;

    k_lstm_l0<<<dim3(Bn * 2), dim3(64), 0, stream>>>(
        x, wih_l0, whh_l0, bih_l0, bhh_l0,
        wih_l0r, whh_l0r, bih_l0r, bhh_l0r, h0);
    k_lstm_l1f<<<dim3(Bn), dim3(192), 0, stream>>>(
        h0, wih_l1, whh_l1, bih_l1, bhh_l1, h1last);
    k_l1r_fc<<<dim3(Bn), dim3(64), 0, stream>>>(
        h0, wih_l1r, bih_l1r, bhh_l1r, h1last, fcw, fcb, (float*)d_out);
}